// Round 14
// baseline (58.341 us; speedup 1.0000x reference)
//
#include <hip/hip_runtime.h>
#include <math.h>

#define NB 128     // BATCH

typedef short s16x8 __attribute__((ext_vector_type(8)));
typedef float f32x16 __attribute__((ext_vector_type(16)));
typedef float f32x4 __attribute__((ext_vector_type(4)));

// workspace layout (byte offsets)
#define WSB_GPART 0u                       // 128 chunks * 16384 bf16 = 4 MB
#define WSB_GH    4194304u                 // 16384 bf16 = 32 KB
#define WSB_T     4227072u                 // 128 fp32
#define WSB_CNT   4227584u                 // 1 u32 barrier counter

static __device__ __forceinline__ unsigned short f2bf(float f) {
    unsigned int u = __float_as_uint(f);
    return (unsigned short)((u + 0x7fffu + ((u >> 16) & 1u)) >> 16);
}
static __device__ __forceinline__ float bf2f(unsigned short h) {
    return __uint_as_float(((unsigned int)h) << 16);
}

// ---------------------------------------------------------------------------
// Kernel 1 (fused gram+reduce with software barrier):
//  blocks 0..127: gram K-chunk partials (K=128 cols, 16 waves = 16 tiles,
//    W read once) -> release-increment counter -> spin until all 128 done ->
//    reduce 128 partials for own 128 G-outputs -> Gh (bf16).
//  blocks 128/129: trace vector t[i] = sum_a W[i,a,a]; no barrier.
// All 130 blocks co-resident (<= 256 CUs) -> spin is safe.
// ---------------------------------------------------------------------------
__global__ __launch_bounds__(1024) void k_gramred(const float* __restrict__ W,
                                                  unsigned short* __restrict__ gpart,
                                                  unsigned short* __restrict__ Gh,
                                                  float* __restrict__ tvec,
                                                  unsigned int* __restrict__ cnt) {
    __shared__ __align__(16) char LDSB[36864];
    const int blk = blockIdx.x;
    const int t = threadIdx.x;   // 0..1023

    if (blk >= 128) {
        // trace: 64 i per block, 16 lanes per i
        const int i = (blk - 128) * 64 + (t >> 4);
        const int a0 = (t & 15) * 8;
        float s = 0.f;
        #pragma unroll
        for (int a = a0; a < a0 + 8; ++a)
            s += W[(size_t)i * 16384 + a * 129];
        s += __shfl_down(s, 8, 16);
        s += __shfl_down(s, 4, 16);
        s += __shfl_down(s, 2, 16);
        s += __shfl_down(s, 1, 16);
        if ((t & 15) == 0) tvec[i] = s;
        return;
    }

    // ---- phase A: gram partials for K-chunk blk
    char* WS = LDSB;             // 32 KB [128 rows][128 k] bf16 swz
    const int kc = blk;
    #pragma unroll
    for (int rep = 0; rep < 4; ++rep) {
        int ch = rep * 1024 + t;
        int row = ch >> 5, f4 = ch & 31;
        float4 w4 = *reinterpret_cast<const float4*>(
            W + (size_t)row * 16384 + kc * 128 + f4 * 4);
        ushort4 h = make_ushort4(f2bf(w4.x), f2bf(w4.y), f2bf(w4.z), f2bf(w4.w));
        *reinterpret_cast<ushort4*>(WS + row * 256 + ((f4 * 8) ^ ((row & 7) << 4))) = h;
    }
    __syncthreads();

    {
        const int wid = t >> 6, l = t & 63;
        const int lr = l & 31, lhi = l >> 5;
        const int r = wid >> 2;
        const int c = wid & 3;
        f32x16 acc;
        #pragma unroll
        for (int i = 0; i < 16; ++i) acc[i] = 0.f;
        const int arow = r * 32 + lr;
        const int brow = c * 32 + lr;
        #pragma unroll
        for (int kk = 0; kk < 8; ++kk) {
            int kb = kk * 32 + lhi * 16;
            s16x8 a = *reinterpret_cast<const s16x8*>(WS + arow * 256 + (kb ^ ((arow & 7) << 4)));
            s16x8 bb = *reinterpret_cast<const s16x8*>(WS + brow * 256 + (kb ^ ((brow & 7) << 4)));
            acc = __builtin_amdgcn_mfma_f32_32x32x16_bf16(a, bb, acc, 0, 0, 0);
        }
        unsigned short* gp = gpart + (size_t)kc * 16384;
        #pragma unroll
        for (int reg = 0; reg < 16; ++reg) {
            int row = r * 32 + (reg & 3) + 8 * (reg >> 2) + 4 * lhi;
            gp[row * 128 + c * 32 + lr] = f2bf(acc[reg]);
        }
    }
    __syncthreads();             // drain all stores (vmcnt) before signaling

    // ---- software barrier across the 128 gram blocks
    if (t == 0) {
        __hip_atomic_fetch_add(cnt, 1u, __ATOMIC_RELEASE, __HIP_MEMORY_SCOPE_AGENT);
        while (__hip_atomic_load(cnt, __ATOMIC_ACQUIRE, __HIP_MEMORY_SCOPE_AGENT) < 128u)
            __builtin_amdgcn_s_sleep(32);
    }
    __syncthreads();

    // ---- phase B: reduce partials -> Gh (block owns outputs blk*128..+127)
    {
        float* red  = (float*)LDSB;              // [64][128] 32 KB
        float* red2 = (float*)(LDSB + 32768);    // [8][128] 4 KB
        const int og  = t & 15;                  // 16 groups x 8 outputs
        const int cgi = t >> 4;                  // 0..63, 2 chunks each
        float a8[8];
        #pragma unroll
        for (int e = 0; e < 8; ++e) a8[e] = 0.f;
        const unsigned short* base = gpart + blk * 128 + og * 8;
        #pragma unroll
        for (int c = 0; c < 2; ++c) {
            uint4 u = *reinterpret_cast<const uint4*>(base + (size_t)(cgi * 2 + c) * 16384);
            const unsigned short* hp = reinterpret_cast<const unsigned short*>(&u);
            #pragma unroll
            for (int e = 0; e < 8; ++e) a8[e] += bf2f(hp[e]);
        }
        #pragma unroll
        for (int e = 0; e < 8; ++e) red[cgi * 128 + og * 8 + e] = a8[e];
        __syncthreads();
        {
            const int o = t & 127, g = t >> 7;
            float s = 0.f;
            #pragma unroll
            for (int j = 0; j < 8; ++j) s += red[(g * 8 + j) * 128 + o];
            red2[g * 128 + o] = s;
        }
        __syncthreads();
        if (t < 128) {
            float s = 0.f;
            #pragma unroll
            for (int g = 0; g < 8; ++g) s += red2[g * 128 + t];
            Gh[blk * 128 + t] = f2bf(s);
        }
    }
}

// ---------------------------------------------------------------------------
// Kernel 2 (fused pv+den+out): block (b, nh), 1024 threads (16 waves).
//   Y = Xb G (8 tiles / waves 0-7, acc in regs), v (wave 8), flags (wave 9);
//   barrier; YS written into GS's first 16 KB (G dead after Y's MFMAs);
//   P = (Y Xb^T)*scale (4 tiles / waves 0-3) -> PS; full denominator
//   (all 1024 threads, duplicated in both nh blocks); write 32 slabs,
//   16 waves, NT f32x4 stores. LDS ~ 66 KiB.
// ---------------------------------------------------------------------------
__global__ __launch_bounds__(1024) void k_pvout(const float* __restrict__ x,
                                                const unsigned short* __restrict__ Gh,
                                                const float* __restrict__ tvec,
                                                const float* __restrict__ seq,
                                                float* __restrict__ out) {
    __shared__ char XS[16384];   // [64 jets][128] bf16 swz
    __shared__ char GS[32768];   // [128][128] bf16 swz; first 16 KB reused as YS
    __shared__ float PS[64 * 64];
    __shared__ float ts[128];
    __shared__ float vls[64];
    __shared__ int   flg[64];
    __shared__ float wred[16];
    __shared__ float sinv_s;
    char* YS = GS;               // alias: [64 rows][128] bf16 swz
    const int b  = blockIdx.x;   // 0..127
    const int nh = blockIdx.y;   // 0..1
    const int t = threadIdx.x;   // 0..1023

    // stage Xb: 2048 float4, 2/thread
    #pragma unroll
    for (int rep = 0; rep < 2; ++rep) {
        int ch = rep * 1024 + t;
        int row = ch >> 5, f4 = ch & 31;
        float4 x4 = *reinterpret_cast<const float4*>(
            x + (size_t)row * 16384 + b * 128 + f4 * 4);
        ushort4 h = make_ushort4(f2bf(x4.x), f2bf(x4.y), f2bf(x4.z), f2bf(x4.w));
        *reinterpret_cast<ushort4*>(XS + row * 256 + ((f4 * 8) ^ ((row & 7) << 4))) = h;
    }
    // stage Gh: 2048 16B chunks, 2/thread
    #pragma unroll
    for (int rep = 0; rep < 2; ++rep) {
        int ch = rep * 1024 + t;
        int row = ch >> 4, kb = ch & 15;
        uint4 g4 = *reinterpret_cast<const uint4*>(Gh + row * 128 + kb * 8);
        *reinterpret_cast<uint4*>(GS + row * 256 + ((kb * 16) ^ ((row & 7) << 4))) = g4;
    }
    if (t < 128) ts[t] = tvec[t];
    __syncthreads();

    const int wid = t >> 6, l = t & 63, lr = l & 31, lhi = l >> 5;

    // ---- Y: waves 0-7 compute tile (wid>>2, wid&3) into registers;
    //      wave 8: v; wave 9: flags
    f32x16 acc;
    if (wid < 8) {
        #pragma unroll
        for (int i = 0; i < 16; ++i) acc[i] = 0.f;
        const int arow = (wid >> 2) * 32 + lr;
        const int brow = (wid & 3) * 32 + lr;
        #pragma unroll
        for (int kk = 0; kk < 8; ++kk) {
            int kb = kk * 32 + lhi * 16;
            s16x8 a = *reinterpret_cast<const s16x8*>(XS + arow * 256 + (kb ^ ((arow & 7) << 4)));
            s16x8 g = *reinterpret_cast<const s16x8*>(GS + brow * 256 + (kb ^ ((brow & 7) << 4)));
            acc = __builtin_amdgcn_mfma_f32_32x32x16_bf16(a, g, acc, 0, 0, 0);
        }
    } else if (wid == 8) {
        float s = 0.f;
        #pragma unroll
        for (int kb = 0; kb < 16; ++kb) {
            uint4 c4 = *reinterpret_cast<const uint4*>(
                XS + l * 256 + ((kb * 16) ^ ((l & 7) << 4)));
            const unsigned short* hp = reinterpret_cast<const unsigned short*>(&c4);
            #pragma unroll
            for (int e = 0; e < 8; ++e)
                s += bf2f(hp[e]) * ts[kb * 8 + e];
        }
        vls[l] = s;
    } else if (wid == 9) {
        flg[l] = (seq[l * NB + b] > 0.f) ? 1 : 0;
    }
    __syncthreads();   // all GS reads done

    // ---- write Y (bf16) into YS (= GS first 16 KB)
    if (wid < 8) {
        #pragma unroll
        for (int reg = 0; reg < 16; ++reg) {
            int row = (wid >> 2) * 32 + (reg & 3) + 8 * (reg >> 2) + 4 * lhi;
            int col = (wid & 3) * 32 + lr;
            *reinterpret_cast<unsigned short*>(
                YS + row * 256 + ((2 * col) ^ ((row & 7) << 4))) = f2bf(acc[reg]);
        }
    }
    __syncthreads();

    // ---- full P (waves 0..3)
    if (wid < 4) {
        f32x16 pa;
        #pragma unroll
        for (int i = 0; i < 16; ++i) pa[i] = 0.f;
        const int arow = (wid >> 1) * 32 + lr;   // Y row (n)
        const int brow = (wid & 1) * 32 + lr;    // jet m
        #pragma unroll
        for (int kk = 0; kk < 8; ++kk) {
            int kb = kk * 32 + lhi * 16;
            s16x8 a = *reinterpret_cast<const s16x8*>(YS + arow * 256 + (kb ^ ((arow & 7) << 4)));
            s16x8 bb = *reinterpret_cast<const s16x8*>(XS + brow * 256 + (kb ^ ((brow & 7) << 4)));
            pa = __builtin_amdgcn_mfma_f32_32x32x16_bf16(a, bb, pa, 0, 0, 0);
        }
        const float SCALE = 1.0f / (128.0f * 128.0f * sqrtf(128.0f));
        #pragma unroll
        for (int reg = 0; reg < 16; ++reg) {
            int n = (wid >> 1) * 32 + (reg & 3) + 8 * (reg >> 2) + 4 * lhi;
            int m = (wid & 1) * 32 + lr;
            PS[n * 64 + m] = pa[reg] * SCALE;
        }
    }
    __syncthreads();

    // ---- FULL denominator: thread t -> (n = t>>4, m = (t&15)*4 + j)
    {
        const int n = t >> 4;
        const int m0 = (t & 15) * 4;
        float a[4];
        int ok[4];
        const int fln = flg[n];
        int anyok = 0;
        #pragma unroll
        for (int j = 0; j < 4; ++j) {
            a[j] = PS[n * 64 + m0 + j];
            ok[j] = fln && flg[m0 + j] && (n != (m0 + j));
            anyok |= ok[j];
        }
        float s = 0.f;
        if (__any(anyok)) {
            for (int ll = 0; ll < 64; ++ll) {
                if (!flg[ll]) continue;        // wave-uniform skip
                float vv = vls[ll];
                #pragma unroll
                for (int j = 0; j < 4; ++j)
                    s += ok[j] ? __expf(a[j] * vv) : 0.f;
            }
            #pragma unroll
            for (int j = 0; j < 4; ++j)
                if (ok[j])
                    s -= __expf(a[j] * vls[n]) + __expf(a[j] * vls[m0 + j]);
        }
        #pragma unroll
        for (int off = 32; off > 0; off >>= 1) s += __shfl_down(s, off, 64);
        if (l == 0) wred[wid] = s;
        __syncthreads();
        if (t == 0) {
            float tot = 0.f;
            #pragma unroll
            for (int w = 0; w < 16; ++w) tot += wred[w];
            sinv_s = 1.0f / tot;
        }
    }
    __syncthreads();

    // ---- write output: 32 slabs (n = nh*32 .. +31), 2 per wave, NT stores
    const float inv = sinv_s;
    const int l0 = (l & 15) * 4;
    const float vv0 = vls[l0], vv1 = vls[l0 + 1], vv2 = vls[l0 + 2], vv3 = vls[l0 + 3];
    const int   fv0 = flg[l0], fv1 = flg[l0 + 1], fv2 = flg[l0 + 2], fv3 = flg[l0 + 3];

    #pragma unroll
    for (int s = 0; s < 2; ++s) {
        const int nl = wid * 2 + s;           // 0..31
        const int n  = nh * 32 + nl;
        float* slabp = out + ((size_t)b << 18) + ((size_t)n << 12);
        if (!flg[n]) {
            f32x4 z = {0.f, 0.f, 0.f, 0.f};
            #pragma unroll
            for (int it = 0; it < 16; ++it)
                __builtin_nontemporal_store(z,
                    reinterpret_cast<f32x4*>(slabp + it * 256 + (l >> 4) * 64 + l0));
            continue;
        }
        #pragma unroll
        for (int it = 0; it < 16; ++it) {
            const int m = it * 4 + (l >> 4);
            const float a = PS[n * 64 + m];
            const bool okm = flg[m] && (m != n);
            f32x4 o;
            o[0] = (okm && fv0 && (l0     != n) && (l0     != m)) ? __expf(a * vv0) * inv : 0.f;
            o[1] = (okm && fv1 && (l0 + 1 != n) && (l0 + 1 != m)) ? __expf(a * vv1) * inv : 0.f;
            o[2] = (okm && fv2 && (l0 + 2 != n) && (l0 + 2 != m)) ? __expf(a * vv2) * inv : 0.f;
            o[3] = (okm && fv3 && (l0 + 3 != n) && (l0 + 3 != m)) ? __expf(a * vv3) * inv : 0.f;
            __builtin_nontemporal_store(o,
                reinterpret_cast<f32x4*>(slabp + (size_t)m * 64 + l0));
        }
    }
}

// ---------------------------------------------------------------------------
extern "C" void kernel_launch(void* const* d_in, const int* in_sizes, int n_in,
                              void* d_out, int out_size, void* d_ws, size_t ws_size,
                              hipStream_t stream) {
    const float* x   = (const float*)d_in[0];
    const float* seq = (const float*)d_in[1];
    const float* W   = (const float*)d_in[2];
    char* wsb = (char*)d_ws;
    unsigned short* gpart = (unsigned short*)(wsb + WSB_GPART);
    unsigned short* Gh    = (unsigned short*)(wsb + WSB_GH);
    float*          tvec  = (float*)(wsb + WSB_T);
    unsigned int*   cnt   = (unsigned int*)(wsb + WSB_CNT);
    float* out = (float*)d_out;

    hipMemsetAsync((void*)cnt, 0, 4, stream);
    k_gramred<<<130, 1024, 0, stream>>>(W, gpart, Gh, tvec, cnt);
    k_pvout  <<<dim3(128, 2), 1024, 0, stream>>>(x, Gh, tvec, seq, out);
}

// Round 15
// 49.167 us; speedup vs baseline: 1.1866x; 1.1866x over previous
//
#include <hip/hip_runtime.h>
#include <math.h>

#define NB 128     // BATCH

typedef short s16x8 __attribute__((ext_vector_type(8)));
typedef float f32x16 __attribute__((ext_vector_type(16)));
typedef float f32x4 __attribute__((ext_vector_type(4)));

// workspace layout (byte offsets)
#define WSB_GPART 0u                       // 128 chunks * 16384 bf16 = 4 MB
#define WSB_GH    4194304u                 // 16384 bf16 = 32 KB
#define WSB_T     4227072u                 // 128 fp32

static __device__ __forceinline__ unsigned short f2bf(float f) {
    unsigned int u = __float_as_uint(f);
    return (unsigned short)((u + 0x7fffu + ((u >> 16) & 1u)) >> 16);
}
static __device__ __forceinline__ float bf2f(unsigned short h) {
    return __uint_as_float(((unsigned int)h) << 16);
}

// ---------------------------------------------------------------------------
// Kernel 1: blocks 0..127: gram partials via MFMA (G = Wf Wf^T, Wf=(128,16384),
// chunk = 128 k-cols, 16 waves = all 16 32x32 tiles, W read once).
// Blocks 128..129: trace vector t[i] = sum_a W[i,a,a].
// ---------------------------------------------------------------------------
__global__ __launch_bounds__(1024) void k_gram(const float* __restrict__ W,
                                               unsigned short* __restrict__ gpart,
                                               float* __restrict__ tvec) {
    __shared__ char WS[32768];   // [128 rows][128 k] bf16, XOR-swizzled
    const int blk = blockIdx.x;
    const int t = threadIdx.x;   // 0..1023

    if (blk >= 128) {
        const int i = (blk - 128) * 64 + (t >> 4);
        const int a0 = (t & 15) * 8;
        float s = 0.f;
        #pragma unroll
        for (int a = a0; a < a0 + 8; ++a)
            s += W[(size_t)i * 16384 + a * 129];
        s += __shfl_down(s, 8, 16);
        s += __shfl_down(s, 4, 16);
        s += __shfl_down(s, 2, 16);
        s += __shfl_down(s, 1, 16);
        if ((t & 15) == 0) tvec[i] = s;
        return;
    }

    const int kc = blk;          // 0..127
    #pragma unroll
    for (int rep = 0; rep < 4; ++rep) {
        int ch = rep * 1024 + t;
        int row = ch >> 5, f4 = ch & 31;
        float4 w4 = *reinterpret_cast<const float4*>(
            W + (size_t)row * 16384 + kc * 128 + f4 * 4);
        ushort4 h = make_ushort4(f2bf(w4.x), f2bf(w4.y), f2bf(w4.z), f2bf(w4.w));
        *reinterpret_cast<ushort4*>(WS + row * 256 + ((f4 * 8) ^ ((row & 7) << 4))) = h;
    }
    __syncthreads();

    const int wid = t >> 6, l = t & 63;
    const int lr = l & 31, lhi = l >> 5;
    const int r = wid >> 2;              // output row-tile 0..3
    const int c = wid & 3;               // output col-tile 0..3

    f32x16 acc;
    #pragma unroll
    for (int i = 0; i < 16; ++i) acc[i] = 0.f;

    const int arow = r * 32 + lr;
    const int brow = c * 32 + lr;
    #pragma unroll
    for (int kk = 0; kk < 8; ++kk) {
        int kb = kk * 32 + lhi * 16;
        s16x8 a = *reinterpret_cast<const s16x8*>(WS + arow * 256 + (kb ^ ((arow & 7) << 4)));
        s16x8 bb = *reinterpret_cast<const s16x8*>(WS + brow * 256 + (kb ^ ((brow & 7) << 4)));
        acc = __builtin_amdgcn_mfma_f32_32x32x16_bf16(a, bb, acc, 0, 0, 0);
    }

    unsigned short* gp = gpart + (size_t)kc * 16384;
    #pragma unroll
    for (int reg = 0; reg < 16; ++reg) {
        int row = r * 32 + (reg & 3) + 8 * (reg >> 2) + 4 * lhi;
        gp[row * 128 + c * 32 + lr] = f2bf(acc[reg]);
    }
}

// ---------------------------------------------------------------------------
// Kernel 2: reduce bf16 partials -> Gh. Block owns 128 outputs; thread
// (og = t&15 -> 8 outputs, cg = t>>4 -> 8 chunks) does 8 independent uint4
// loads, then 2-stage LDS reduce.
// ---------------------------------------------------------------------------
__global__ __launch_bounds__(256) void k_gred(const unsigned short* __restrict__ gpart,
                                              unsigned short* __restrict__ Gh) {
    __shared__ float red[16 * 128];
    const int blk = blockIdx.x;      // 0..127
    const int t = threadIdx.x;       // 0..255
    const int og = t & 15;
    const int cg = t >> 4;

    float acc[8];
    #pragma unroll
    for (int e = 0; e < 8; ++e) acc[e] = 0.f;

    const unsigned short* base = gpart + blk * 128 + og * 8;
    #pragma unroll
    for (int c = 0; c < 8; ++c) {
        uint4 u = *reinterpret_cast<const uint4*>(base + (size_t)(cg * 8 + c) * 16384);
        const unsigned short* hp = reinterpret_cast<const unsigned short*>(&u);
        #pragma unroll
        for (int e = 0; e < 8; ++e) acc[e] += bf2f(hp[e]);
    }
    #pragma unroll
    for (int e = 0; e < 8; ++e) red[cg * 128 + og * 8 + e] = acc[e];
    __syncthreads();

    if (t < 128) {
        float s = 0.f;
        #pragma unroll
        for (int g = 0; g < 16; ++g) s += red[g * 128 + t];
        Gh[blk * 128 + t] = f2bf(s);
    }
}

// ---------------------------------------------------------------------------
// Kernel 3 (fused pv+den+out): block (b, nh), 1024 threads (16 waves).
//   Y = Xb G (8 tiles / waves 0-7, acc in regs), v (wave 8), flags (wave 9);
//   barrier; YS written into GS's first 16 KB (G is dead after Y's MFMAs);
//   P = (Y Xb^T)*scale (4 tiles / waves 0-3) -> PS; full denominator
//   (all 1024 threads, duplicated in both nh blocks); write 32 slabs with
//   16 waves (NT f32x4 stores). LDS ~ 66 KiB.
// ---------------------------------------------------------------------------
__global__ __launch_bounds__(1024) void k_pvout(const float* __restrict__ x,
                                                const unsigned short* __restrict__ Gh,
                                                const float* __restrict__ tvec,
                                                const float* __restrict__ seq,
                                                float* __restrict__ out) {
    __shared__ char XS[16384];   // [64 jets][128] bf16 swz
    __shared__ char GS[32768];   // [128][128] bf16 swz; first 16 KB reused as YS
    __shared__ float PS[64 * 64];
    __shared__ float ts[128];
    __shared__ float vls[64];
    __shared__ int   flg[64];
    __shared__ float wred[16];
    __shared__ float sinv_s;
    char* YS = GS;               // alias: [64 rows][128] bf16 swz
    const int b  = blockIdx.x;   // 0..127
    const int nh = blockIdx.y;   // 0..1
    const int t = threadIdx.x;   // 0..1023

    // stage Xb: 2048 float4, 2/thread
    #pragma unroll
    for (int rep = 0; rep < 2; ++rep) {
        int ch = rep * 1024 + t;
        int row = ch >> 5, f4 = ch & 31;
        float4 x4 = *reinterpret_cast<const float4*>(
            x + (size_t)row * 16384 + b * 128 + f4 * 4);
        ushort4 h = make_ushort4(f2bf(x4.x), f2bf(x4.y), f2bf(x4.z), f2bf(x4.w));
        *reinterpret_cast<ushort4*>(XS + row * 256 + ((f4 * 8) ^ ((row & 7) << 4))) = h;
    }
    // stage Gh: 2048 16B chunks, 2/thread
    #pragma unroll
    for (int rep = 0; rep < 2; ++rep) {
        int ch = rep * 1024 + t;
        int row = ch >> 4, kb = ch & 15;
        uint4 g4 = *reinterpret_cast<const uint4*>(Gh + row * 128 + kb * 8);
        *reinterpret_cast<uint4*>(GS + row * 256 + ((kb * 16) ^ ((row & 7) << 4))) = g4;
    }
    if (t < 128) ts[t] = tvec[t];
    __syncthreads();

    const int wid = t >> 6, l = t & 63, lr = l & 31, lhi = l >> 5;

    // ---- Y: waves 0-7 compute tile (wid>>2, wid&3) into registers;
    //      wave 8: v; wave 9: flags
    f32x16 acc;
    if (wid < 8) {
        #pragma unroll
        for (int i = 0; i < 16; ++i) acc[i] = 0.f;
        const int arow = (wid >> 2) * 32 + lr;
        const int brow = (wid & 3) * 32 + lr;
        #pragma unroll
        for (int kk = 0; kk < 8; ++kk) {
            int kb = kk * 32 + lhi * 16;
            s16x8 a = *reinterpret_cast<const s16x8*>(XS + arow * 256 + (kb ^ ((arow & 7) << 4)));
            s16x8 g = *reinterpret_cast<const s16x8*>(GS + brow * 256 + (kb ^ ((brow & 7) << 4)));
            acc = __builtin_amdgcn_mfma_f32_32x32x16_bf16(a, g, acc, 0, 0, 0);
        }
    } else if (wid == 8) {
        float s = 0.f;
        #pragma unroll
        for (int kb = 0; kb < 16; ++kb) {
            uint4 c4 = *reinterpret_cast<const uint4*>(
                XS + l * 256 + ((kb * 16) ^ ((l & 7) << 4)));
            const unsigned short* hp = reinterpret_cast<const unsigned short*>(&c4);
            #pragma unroll
            for (int e = 0; e < 8; ++e)
                s += bf2f(hp[e]) * ts[kb * 8 + e];
        }
        vls[l] = s;
    } else if (wid == 9) {
        flg[l] = (seq[l * NB + b] > 0.f) ? 1 : 0;
    }
    __syncthreads();   // all GS reads done

    // ---- write Y (bf16) into YS (= GS first 16 KB)
    if (wid < 8) {
        #pragma unroll
        for (int reg = 0; reg < 16; ++reg) {
            int row = (wid >> 2) * 32 + (reg & 3) + 8 * (reg >> 2) + 4 * lhi;
            int col = (wid & 3) * 32 + lr;
            *reinterpret_cast<unsigned short*>(
                YS + row * 256 + ((2 * col) ^ ((row & 7) << 4))) = f2bf(acc[reg]);
        }
    }
    __syncthreads();

    // ---- full P (waves 0..3)
    if (wid < 4) {
        f32x16 pa;
        #pragma unroll
        for (int i = 0; i < 16; ++i) pa[i] = 0.f;
        const int arow = (wid >> 1) * 32 + lr;   // Y row (n)
        const int brow = (wid & 1) * 32 + lr;    // jet m
        #pragma unroll
        for (int kk = 0; kk < 8; ++kk) {
            int kb = kk * 32 + lhi * 16;
            s16x8 a = *reinterpret_cast<const s16x8*>(YS + arow * 256 + (kb ^ ((arow & 7) << 4)));
            s16x8 bb = *reinterpret_cast<const s16x8*>(XS + brow * 256 + (kb ^ ((brow & 7) << 4)));
            pa = __builtin_amdgcn_mfma_f32_32x32x16_bf16(a, bb, pa, 0, 0, 0);
        }
        const float SCALE = 1.0f / (128.0f * 128.0f * sqrtf(128.0f));
        #pragma unroll
        for (int reg = 0; reg < 16; ++reg) {
            int n = (wid >> 1) * 32 + (reg & 3) + 8 * (reg >> 2) + 4 * lhi;
            int m = (wid & 1) * 32 + lr;
            PS[n * 64 + m] = pa[reg] * SCALE;
        }
    }
    __syncthreads();

    // ---- FULL denominator: thread t -> (n = t>>4, m = (t&15)*4 + j)
    {
        const int n = t >> 4;
        const int m0 = (t & 15) * 4;
        float a[4];
        int ok[4];
        const int fln = flg[n];
        int anyok = 0;
        #pragma unroll
        for (int j = 0; j < 4; ++j) {
            a[j] = PS[n * 64 + m0 + j];
            ok[j] = fln && flg[m0 + j] && (n != (m0 + j));
            anyok |= ok[j];
        }
        float s = 0.f;
        if (__any(anyok)) {
            for (int ll = 0; ll < 64; ++ll) {
                if (!flg[ll]) continue;        // wave-uniform skip
                float vv = vls[ll];
                #pragma unroll
                for (int j = 0; j < 4; ++j)
                    s += ok[j] ? __expf(a[j] * vv) : 0.f;
            }
            #pragma unroll
            for (int j = 0; j < 4; ++j)
                if (ok[j])
                    s -= __expf(a[j] * vls[n]) + __expf(a[j] * vls[m0 + j]);
        }
        #pragma unroll
        for (int off = 32; off > 0; off >>= 1) s += __shfl_down(s, off, 64);
        if (l == 0) wred[wid] = s;
        __syncthreads();
        if (t == 0) {
            float tot = 0.f;
            #pragma unroll
            for (int w = 0; w < 16; ++w) tot += wred[w];
            sinv_s = 1.0f / tot;
        }
    }
    __syncthreads();

    // ---- write output: 32 slabs (n = nh*32 .. +31), 2 per wave, NT stores
    const float inv = sinv_s;
    const int l0 = (l & 15) * 4;
    const float vv0 = vls[l0], vv1 = vls[l0 + 1], vv2 = vls[l0 + 2], vv3 = vls[l0 + 3];
    const int   fv0 = flg[l0], fv1 = flg[l0 + 1], fv2 = flg[l0 + 2], fv3 = flg[l0 + 3];

    #pragma unroll
    for (int s = 0; s < 2; ++s) {
        const int nl = wid * 2 + s;           // 0..31
        const int n  = nh * 32 + nl;
        float* slabp = out + ((size_t)b << 18) + ((size_t)n << 12);
        if (!flg[n]) {
            f32x4 z = {0.f, 0.f, 0.f, 0.f};
            #pragma unroll
            for (int it = 0; it < 16; ++it)
                __builtin_nontemporal_store(z,
                    reinterpret_cast<f32x4*>(slabp + it * 256 + (l >> 4) * 64 + l0));
            continue;
        }
        #pragma unroll
        for (int it = 0; it < 16; ++it) {
            const int m = it * 4 + (l >> 4);
            const float a = PS[n * 64 + m];
            const bool okm = flg[m] && (m != n);
            f32x4 o;
            o[0] = (okm && fv0 && (l0     != n) && (l0     != m)) ? __expf(a * vv0) * inv : 0.f;
            o[1] = (okm && fv1 && (l0 + 1 != n) && (l0 + 1 != m)) ? __expf(a * vv1) * inv : 0.f;
            o[2] = (okm && fv2 && (l0 + 2 != n) && (l0 + 2 != m)) ? __expf(a * vv2) * inv : 0.f;
            o[3] = (okm && fv3 && (l0 + 3 != n) && (l0 + 3 != m)) ? __expf(a * vv3) * inv : 0.f;
            __builtin_nontemporal_store(o,
                reinterpret_cast<f32x4*>(slabp + (size_t)m * 64 + l0));
        }
    }
}

// ---------------------------------------------------------------------------
extern "C" void kernel_launch(void* const* d_in, const int* in_sizes, int n_in,
                              void* d_out, int out_size, void* d_ws, size_t ws_size,
                              hipStream_t stream) {
    const float* x   = (const float*)d_in[0];
    const float* seq = (const float*)d_in[1];
    const float* W   = (const float*)d_in[2];
    char* wsb = (char*)d_ws;
    unsigned short* gpart = (unsigned short*)(wsb + WSB_GPART);
    unsigned short* Gh    = (unsigned short*)(wsb + WSB_GH);
    float*          tvec  = (float*)(wsb + WSB_T);
    float* out = (float*)d_out;

    k_gram <<<130, 1024, 0, stream>>>(W, gpart, tvec);
    k_gred <<<128, 256, 0, stream>>>(gpart, Gh);
    k_pvout<<<dim3(128, 2), 1024, 0, stream>>>(x, Gh, tvec, seq, out);
}